// Round 12
// baseline (299.039 us; speedup 1.0000x reference)
//
#include <hip/hip_runtime.h>
#include <stdint.h>

typedef unsigned short u16;
typedef __attribute__((ext_vector_type(8))) __bf16 bf16x8;
typedef __attribute__((ext_vector_type(4))) float f32x4;

#define BSD 6291456   // 4*2048*768
#define WSZ 589824    // 768*768
#define QSCALE 0.18033688011112042f   // log2(e)/8, folded into Q projection

#if __has_builtin(__builtin_amdgcn_exp2f)
#define EXP2(x) __builtin_amdgcn_exp2f(x)
#else
#define EXP2(x) __builtin_exp2f(x)
#endif

__device__ __forceinline__ uint32_t fbits(float f) {
  union { float f; uint32_t u; } v; v.f = f; return v.u;
}
__device__ __forceinline__ u16 f2bf(float f) {           // RNE (epilogue scalar use only)
  uint32_t u = fbits(f);
  return (u16)((u + 0x7fff + ((u >> 16) & 1)) >> 16);
}
// round-to-nearest (half-up) bf16 pack of two floats via v_perm_b32: 3 insts / 2 values
__device__ __forceinline__ uint32_t pack_bf16rn(float lo, float hi) {
  return __builtin_amdgcn_perm(fbits(hi) + 0x8000u, fbits(lo) + 0x8000u, 0x07060302u);
}

__device__ __forceinline__ void load_lds16(const u16* g, u16* l) {
  __builtin_amdgcn_global_load_lds((__attribute__((address_space(1))) void*)(void*)g,
                                   (__attribute__((address_space(3))) void*)l, 16, 0, 0);
}

__device__ __forceinline__ f32x4 mfma16(bf16x8 a, bf16x8 b, f32x4 c) {
  return __builtin_amdgcn_mfma_f32_16x16x32_bf16(a, b, c, 0, 0, 0);
}

// ---------------- fp32 -> bf16 conversion of the 4 weight matrices only ----------------
// Round-12: q/k/v are no longer pre-converted — gemm_qkv reads them as f32 and
// converts during its LDS staging (T14 async reg-stage). Only the weights (2.36M
// elems, reused by many blocks) keep a bf16 copy. 1152 blocks, ~3us.
__global__ void convert_w(const float* __restrict__ wq, const float* __restrict__ wk,
                          const float* __restrict__ wv, const float* __restrict__ wd,
                          u16* __restrict__ dst) {
  long e = ((long)blockIdx.x * blockDim.x + threadIdx.x) * 8;
  const float* src;
  if (e < (long)WSZ) src = wq + e;
  else if (e < 2L*WSZ) src = wk + (e - (long)WSZ);
  else if (e < 3L*WSZ) src = wv + (e - 2L*WSZ);
  else src = wd + (e - 3L*WSZ);
  float4 f0 = ((const float4*)src)[0];
  float4 f1 = ((const float4*)src)[1];
  uint4 o;
  o.x = pack_bf16rn(f0.x, f0.y);
  o.y = pack_bf16rn(f0.z, f0.w);
  o.z = pack_bf16rn(f1.x, f1.y);
  o.w = pack_bf16rn(f1.z, f1.w);
  *(uint4*)(dst + e) = o;
}

// ---------------- fused Q+K+V projection, f32-A reg-staged, dbuf K-loop, BM=128 ----
// A rows come straight from the f32 inputs: [0,8192)=q, [8192,16384)=k,
// [16384,24576)=v — the bf16 cast happens during staging:
//   after the barrier: issue 4 float4 A-loads (latency hides under the 16 MFMAs)
//   + B-tile global_load_lds (bf16 weights);
//   end of compute phase: pack f32->bf16 (same pack_bf16rn rounding as the old
//   convert kernel) + ds_write_b128 into buf[(ks+1)&1]. Safe: the barrier at the
//   top of iter ks guarantees all waves finished READING buf[(ks+1)&1] (it was
//   iter ks-1's compute buffer); the next barrier's lgkm drain publishes writes.
// This deletes the 21us convert round-trip for q/k/v (85MB read + 42.5MB write
// + 42.5MB re-read becomes a single 75MB f32 read).
// Per-block role from m0: q -> bf16(val*QSCALE) -> Qh; k -> Kh; v -> TRANSPOSED Vt.
// r8 lesson: Vt lives in the output buffer's aout region (dead until tail_fused)
// so the fusion is race-free. r7 lesson: BM=128.
__global__ __launch_bounds__(256) void gemm_qkv(const float* __restrict__ qf32, const float* __restrict__ kf32,
                                                const float* __restrict__ vf32, const u16* __restrict__ Bw,
                                                u16* __restrict__ Cb, u16* __restrict__ Vt,
                                                int N, int K, float oscale) {
  __shared__ u16 ldsA[2][128*32];
  __shared__ u16 ldsB[2][128*32];
  const int t = threadIdx.x, w = t >> 6, lane = t & 63, quad = lane >> 4, n16 = lane & 15;
  const int gx = gridDim.x, gy = gridDim.y;
  const int nb = gx * gy;
  int bx, by;
  if ((nb & 7) == 0) {
    int bid = (int)blockIdx.y * gx + (int)blockIdx.x;   // hw linear dispatch id
    int lid = (bid & 7) * (nb >> 3) + (bid >> 3);       // XCD-contiguous logical id
    bx = lid / gy; by = lid % gy;                       // same-bx blocks adjacent
  } else {
    bx = blockIdx.x; by = blockIdx.y;
  }
  const int m0 = bx * 128, n0 = by * 128;
  const int wr = (w >> 1) * 64, wc = (w & 1) * 64;
  const u16* Bm = Bw;
  const float* Af;
  float sc = oscale;
  int vsel = 0;
  if (m0 >= 16384)     { Af = vf32 + (size_t)(m0 - 16384)*K; Bm = Bw + 2*WSZ; sc = 1.0f; vsel = 1; }
  else if (m0 >= 8192) { Af = kf32 + (size_t)(m0 - 8192)*K;  Bm = Bw + WSZ;   sc = 1.0f; }
  else                 { Af = qf32 + (size_t)m0*K; }
  // A reg-stage: thread t owns slots {t, 256+t}; slot s = row*4+ch holds
  // A[row][ch*8..+8] (8 bf16 = 16B), identical LDS layout to the old gload path.
  auto loadA = [&](int k0, float4* r) {
#pragma unroll
    for (int j = 0; j < 2; ++j) {
      int slot = j*256 + t, row = slot >> 2, ch = slot & 3;
      const float4* p = (const float4*)(Af + (size_t)row*K + k0 + ch*8);
      r[j*2 + 0] = p[0];
      r[j*2 + 1] = p[1];
    }
  };
  auto writeA = [&](const float4* r, int bs) {
#pragma unroll
    for (int j = 0; j < 2; ++j) {
      int slot = j*256 + t;
      uint4 o;
      o.x = pack_bf16rn(r[j*2].x,     r[j*2].y);
      o.y = pack_bf16rn(r[j*2].z,     r[j*2].w);
      o.z = pack_bf16rn(r[j*2 + 1].x, r[j*2 + 1].y);
      o.w = pack_bf16rn(r[j*2 + 1].z, r[j*2 + 1].w);
      *(uint4*)(&ldsA[bs][0] + slot*8) = o;
    }
  };
  auto stageB = [&](int k0, int bs) {
#pragma unroll
    for (int j = 0; j < 2; ++j) {
      int slot = j*256 + t;
      int row = slot >> 2, ch = slot & 3;
      load_lds16(Bm + (size_t)(n0 + row)*K + k0 + ch*8, &ldsB[bs][0] + slot*8);
    }
  };
  f32x4 acc[4][4] = {};
  const int NK = K >> 5;
  float4 ra[4];
  loadA(0, ra);
  stageB(0, 0);
  writeA(ra, 0);
#pragma unroll 1
  for (int ks = 0; ks < NK; ++ks) {
    __syncthreads();                        // tile ks published (B vmcnt + A lgkm drained)
    if (ks + 1 < NK) {
      loadA((ks + 1) << 5, ra);             // f32 loads issue early; latency hides under MFMAs
      stageB((ks + 1) << 5, (ks + 1) & 1);
    }
    const u16* As = &ldsA[ks & 1][0];
    const u16* Bs = &ldsB[ks & 1][0];
    bf16x8 af[4], bf[4];
#pragma unroll
    for (int i = 0; i < 4; ++i) {
      af[i] = *(const bf16x8*)(As + (wr + i*16 + n16)*32 + quad*8);
      bf[i] = *(const bf16x8*)(Bs + (wc + i*16 + n16)*32 + quad*8);
    }
#pragma unroll
    for (int mi = 0; mi < 4; ++mi)
#pragma unroll
      for (int ni = 0; ni < 4; ++ni)
        acc[mi][ni] = mfma16(af[mi], bf[ni], acc[mi][ni]);
    if (ks + 1 < NK) writeA(ra, (ks + 1) & 1);   // pack + ds_write after compute
  }
#pragma unroll
  for (int mi = 0; mi < 4; ++mi)
#pragma unroll
    for (int ni = 0; ni < 4; ++ni) {
      if (vsel) {
        int c = n0 + wc + ni*16 + n16;                 // feature 0..767
        int hh = c >> 6, d = c & 63;
        int m = m0 + wr + mi*16 + quad*4 - 16384;      // v tokens 0..8191
        int bI = m >> 11, s = m & 2047;
        uint2 pk;
        pk.x = pack_bf16rn(acc[mi][ni][0], acc[mi][ni][1]);
        pk.y = pack_bf16rn(acc[mi][ni][2], acc[mi][ni][3]);
        *(uint2*)(Vt + ((size_t)(bI*12 + hh)*64 + d)*2048 + s) = pk;
      } else {
#pragma unroll
        for (int i = 0; i < 4; ++i) {
          size_t r = (size_t)m0 + wr + mi*16 + quad*4 + i;   // C/D: row=(lane>>4)*4+i
          size_t c = (size_t)n0 + wc + ni*16 + n16;          //      col=lane&15
          Cb[r*(size_t)N + c] = f2bf(acc[mi][ni][i] * sc);
        }
      }
    }
}

// ---------------- fused attention (r5-r11 structure, measured 67-70 us) ----------
__global__ __launch_bounds__(256, 3) void attn_fused(const u16* __restrict__ Qh, const u16* __restrict__ Kh,
                                                     const u16* __restrict__ Vt, u16* __restrict__ ctx,
                                                     float* __restrict__ rowsum) {
  __shared__ u16 ldsK[2*64*64];    // [buf][n][8 chunks of 8 u16], chunk XOR-swizzled by n&7
  __shared__ u16 ldsV[2*64*64];    // [buf][d][8 chunks],          swizzled by d&7
  __shared__ u16 ldsP[128*64];     // [m][8 b128-chunks],          swizzled by m&7; wave-private rows
  const int bid = blockIdx.x;
  const int lid = (bid & 7) * 96 + (bid >> 3);   // XCD-contiguous logical id (bijective, 768%8==0)
  const int pair = lid >> 4;            // 0..47 = (b,h)
  const int qt = lid & 15;              // q-tile
  const int h = pair % 12, b = pair / 12;
  const int q0 = qt * 128;
  const int t = threadIdx.x, w = t >> 6, lane = t & 63, quad = lane >> 4, n16 = lane & 15;
  const int sw = n16 & 7;
  const u16* Kbh = Kh + (size_t)b*2048*768 + h*64;
  const u16* Vbh = Vt + (size_t)(b*12 + h)*64*2048;
  auto stage = [&](int c, int bsel) {
#pragma unroll
    for (int jj = 0; jj < 2; ++jj) {
      int slot = jj*256 + t;                // lane-linear LDS dst
      int n = slot >> 3, cg = (slot & 7) ^ (n & 7);
      load_lds16(Kbh + (size_t)(c*64 + n)*768 + cg*8, ldsK + bsel*4096 + slot*8);
      load_lds16(Vbh + (size_t)n*2048 + c*64 + cg*8, ldsV + bsel*4096 + slot*8);
    }
  };
  // loop-invariant LDS element offsets (u16 units)
  int koff[4][2], voff[2][4], prd[2][2], pwr[2], pwc[4];
#pragma unroll
  for (int ni = 0; ni < 4; ++ni) {
    koff[ni][0] = (ni*16 + n16)*64 + ((quad ^ sw) * 8);
    koff[ni][1] = (ni*16 + n16)*64 + (((4 + quad) ^ sw) * 8);
    pwc[ni] = ((ni*2 + (quad >> 1)) ^ sw) * 8;
  }
#pragma unroll
  for (int kt = 0; kt < 2; ++kt)
#pragma unroll
    for (int di = 0; di < 4; ++di)
      voff[kt][di] = (di*16 + n16)*64 + (((kt*4 + quad) ^ sw) * 8);
#pragma unroll
  for (int mi = 0; mi < 2; ++mi) {
    pwr[mi] = (w*32 + mi*16 + n16)*64 + (quad & 1)*4;
    prd[mi][0] = (w*32 + mi*16 + n16)*64 + ((quad ^ sw) * 8);
    prd[mi][1] = (w*32 + mi*16 + n16)*64 + (((4 + quad) ^ sw) * 8);
  }
  bf16x8 qf[2][2];                 // Q frags (pre-scaled by log2e/8) in regs all kernel
#pragma unroll
  for (int mi = 0; mi < 2; ++mi)
#pragma unroll
    for (int ks = 0; ks < 2; ++ks)
      qf[mi][ks] = *(const bf16x8*)(Qh + (size_t)(b*2048 + q0 + w*32 + mi*16 + n16)*768
                                       + h*64 + ks*32 + quad*8);
  // all-ones B fragment: racc += P @ ones gives rowsums on the MFMA pipe,
  // replicated across n16 and already in C-layout rows (quad*4+i).
  union { uint32_t u[4]; bf16x8 v; } onesu = {{0x3F803F80u, 0x3F803F80u, 0x3F803F80u, 0x3F803F80u}};
  const bf16x8 ones = onesu.v;
  f32x4 oacc[2][4] = {};
  f32x4 racc[2] = {};
  stage(0, 0);
#pragma unroll 1
  for (int c = 0; c < 32; ++c) {
    __syncthreads();                        // chunk c staged (vmcnt drain); prior reads of buf[(c+1)&1] done
    if (c < 31) stage(c + 1, (c + 1) & 1);  // prefetch overlaps this chunk's compute
    const int bs = (c & 1) * 4096;
    const u16* K0 = ldsK + bs;
    const u16* V0 = ldsV + bs;
    f32x4 sacc[4][2] = {};
    __builtin_amdgcn_s_setprio(1);
#pragma unroll
    for (int ni = 0; ni < 4; ++ni) {
      bf16x8 kf0 = *(const bf16x8*)(K0 + koff[ni][0]);
      bf16x8 kf1 = *(const bf16x8*)(K0 + koff[ni][1]);
#pragma unroll
      for (int mi = 0; mi < 2; ++mi) {
        sacc[ni][mi] = mfma16(kf0, qf[mi][0], sacc[ni][mi]);   // S^T = K.Q^T
        sacc[ni][mi] = mfma16(kf1, qf[mi][1], sacc[ni][mi]);
      }
    }
    __builtin_amdgcn_s_setprio(0);
    // exp2 (Q pre-scaled -> 1 v_exp each) + native-cast bf16 pack (no VALU rowsum)
#pragma unroll
    for (int mi = 0; mi < 2; ++mi) {
#pragma unroll
      for (int ni = 0; ni < 4; ++ni) {
        float p0 = EXP2(sacc[ni][mi][0]);
        float p1 = EXP2(sacc[ni][mi][1]);
        float p2 = EXP2(sacc[ni][mi][2]);
        float p3 = EXP2(sacc[ni][mi][3]);
        union { __bf16 bx[4]; uint2 v; } pk;
        pk.bx[0] = (__bf16)p0;
        pk.bx[1] = (__bf16)p1;
        pk.bx[2] = (__bf16)p2;
        pk.bx[3] = (__bf16)p3;
        *(uint2*)(ldsP + pwr[mi] + pwc[ni]) = pk.v;
      }
    }
    // PV: A = P (wave-private rows, no barrier), B = V^T chunk; rowsum rides along.
#pragma unroll
    for (int kt = 0; kt < 2; ++kt) {
      bf16x8 vf[4], pf[2];
#pragma unroll
      for (int di = 0; di < 4; ++di)
        vf[di] = *(const bf16x8*)(V0 + voff[kt][di]);
#pragma unroll
      for (int mi = 0; mi < 2; ++mi)
        pf[mi] = *(const bf16x8*)(ldsP + prd[mi][kt]);
      __builtin_amdgcn_s_setprio(1);
#pragma unroll
      for (int mi = 0; mi < 2; ++mi) {
        racc[mi] = mfma16(pf[mi], ones, racc[mi]);
#pragma unroll
        for (int di = 0; di < 4; ++di)
          oacc[mi][di] = mfma16(pf[mi], vf[di], oacc[mi][di]);
      }
      __builtin_amdgcn_s_setprio(0);
    }
  }
  // racc[mi][i] = full rowsum for row quad*4+i (replicated over n16) — matches oacc layout
  float invr[2][4];
#pragma unroll
  for (int mi = 0; mi < 2; ++mi)
#pragma unroll
    for (int i = 0; i < 4; ++i)
      invr[mi][i] = 1.0f / racc[mi][i];
#pragma unroll
  for (int mi = 0; mi < 2; ++mi)
#pragma unroll
    for (int di = 0; di < 4; ++di)
#pragma unroll
      for (int i = 0; i < 4; ++i) {
        size_t r = (size_t)b*2048 + q0 + w*32 + mi*16 + quad*4 + i;
        int cc = h*64 + di*16 + n16;
        ctx[r*768 + cc] = f2bf(oacc[mi][di][i] * invr[mi][i]);
      }
  if (h == 0 && n16 == 0) {
#pragma unroll
    for (int mi = 0; mi < 2; ++mi)
#pragma unroll
      for (int i = 0; i < 4; ++i)
        rowsum[b*2048 + q0 + w*32 + mi*16 + quad*4 + i] = racc[mi][i];
  }
}

// ---------------- tail_fused: attn_h0 + out-projection in ONE launch (r10 win) ----
__global__ __launch_bounds__(256) void tail_fused(const u16* __restrict__ Qh, const u16* __restrict__ Kh,
                                                  const float* __restrict__ rowsum, float* __restrict__ aout,
                                                  const u16* __restrict__ ctx, const u16* __restrict__ wdb,
                                                  float* __restrict__ out, const float* __restrict__ bias) {
  __shared__ __align__(16) u16 shmem[16384];   // 32 KB; h0 uses 16 KB, gemm all 32 KB
  const int bid = blockIdx.x;
  const int grp = bid / 11, off = bid % 11;
  const int t = threadIdx.x, w = t >> 6, lane = t & 63, quad = lane >> 4, n16 = lane & 15;
  if (off < 8) {
    // ---- h0 role: recompute QK^T for h=0, scale by 1/rowsum ----
    const int idx = grp * 8 + off;            // 0..1023
    const int qt = idx & 15, kt = (idx >> 4) & 15, b = idx >> 8;
    const int q0 = qt * 128;
    u16* ldsK = shmem;                        // [128][64]
    const u16* Kbh = Kh + (size_t)b*2048*768; // h = 0
    bf16x8 qf[2][2];
#pragma unroll
    for (int mi = 0; mi < 2; ++mi)
#pragma unroll
      for (int ks = 0; ks < 2; ++ks)
        qf[mi][ks] = *(const bf16x8*)(Qh + (size_t)(b*2048 + q0 + w*32 + mi*16 + n16)*768
                                         + ks*32 + quad*8);
#pragma unroll
    for (int j = 0; j < 4; ++j) {
      int slot = j*256 + w*64 + lane;
      int n = slot >> 3, cs = slot & 7, cg = cs ^ (n & 7);
      load_lds16(Kbh + (size_t)(kt*128 + n)*768 + cg*8, ldsK + slot*8);
    }
    __syncthreads();
    f32x4 sacc[2][8] = {};
#pragma unroll
    for (int ni = 0; ni < 8; ++ni) {
      int n = ni*16 + n16;
      bf16x8 kf0 = *(const bf16x8*)(ldsK + n*64 + ((quad)     ^ (n & 7))*8);
      bf16x8 kf1 = *(const bf16x8*)(ldsK + n*64 + ((4 + quad) ^ (n & 7))*8);
#pragma unroll
      for (int mi = 0; mi < 2; ++mi) {
        sacc[mi][ni] = mfma16(qf[mi][0], kf0, sacc[mi][ni]);
        sacc[mi][ni] = mfma16(qf[mi][1], kf1, sacc[mi][ni]);
      }
    }
    float inv[2][4];
#pragma unroll
    for (int mi = 0; mi < 2; ++mi)
#pragma unroll
      for (int i = 0; i < 4; ++i)
        inv[mi][i] = 1.0f / rowsum[b*2048 + q0 + w*32 + mi*16 + quad*4 + i];
#pragma unroll
    for (int mi = 0; mi < 2; ++mi)
#pragma unroll
      for (int ni = 0; ni < 8; ++ni)
#pragma unroll
        for (int i = 0; i < 4; ++i) {
          size_t r = (size_t)b*2048 + q0 + w*32 + mi*16 + quad*4 + i;
          size_t cc = (size_t)kt*128 + ni*16 + n16;
          aout[r*2048 + cc] = EXP2(sacc[mi][ni][i]) * inv[mi][i];   // Qh pre-scaled
        }
  } else {
    // ---- out-projection role: out = ctx @ wd^T + bias (BM=128, dbuf K-loop) ----
    const int idx = grp * 3 + (off - 8);      // 0..383
    const int bx = idx & 63, by = idx >> 6;   // (64,6)
    const int m0 = bx * 128, n0 = by * 128;
    const int wr = (w >> 1) * 64, wc = (w & 1) * 64;
    const int K = 768, N = 768;
    u16* ldsA = shmem;                        // [2][128*32] = 8192 u16
    u16* ldsB = shmem + 8192;                 // [2][128*32]
    auto stage = [&](int k0, int bs) {
#pragma unroll
      for (int j = 0; j < 2; ++j) {
        int slot = j*256 + t;
        int row = slot >> 2, ch = slot & 3;
        load_lds16(ctx + (size_t)(m0 + row)*K + k0 + ch*8, ldsA + bs*4096 + slot*8);
        load_lds16(wdb + (size_t)(n0 + row)*K + k0 + ch*8, ldsB + bs*4096 + slot*8);
      }
    };
    f32x4 acc[4][4] = {};
    stage(0, 0);
#pragma unroll 1
    for (int ks = 0; ks < 24; ++ks) {
      __syncthreads();
      if (ks + 1 < 24) stage((ks + 1) << 5, (ks + 1) & 1);
      const u16* As = ldsA + (ks & 1)*4096;
      const u16* Bs = ldsB + (ks & 1)*4096;
      bf16x8 af[4], bf[4];
#pragma unroll
      for (int i = 0; i < 4; ++i) {
        af[i] = *(const bf16x8*)(As + (wr + i*16 + n16)*32 + quad*8);
        bf[i] = *(const bf16x8*)(Bs + (wc + i*16 + n16)*32 + quad*8);
      }
#pragma unroll
      for (int mi = 0; mi < 4; ++mi)
#pragma unroll
        for (int ni = 0; ni < 4; ++ni)
          acc[mi][ni] = mfma16(af[mi], bf[ni], acc[mi][ni]);
    }
#pragma unroll
    for (int mi = 0; mi < 4; ++mi)
#pragma unroll
      for (int ni = 0; ni < 4; ++ni)
#pragma unroll
        for (int i = 0; i < 4; ++i) {
          size_t r = (size_t)m0 + wr + mi*16 + quad*4 + i;
          size_t c = (size_t)n0 + wc + ni*16 + n16;
          out[r*(size_t)N + c] = acc[mi][ni][i] + bias[c];
        }
  }
}

extern "C" void kernel_launch(void* const* d_in, const int* in_sizes, int n_in,
                              void* d_out, int out_size, void* d_ws, size_t ws_size,
                              hipStream_t stream) {
  (void)in_sizes; (void)n_in; (void)out_size; (void)ws_size;
  const float* q  = (const float*)d_in[0];
  const float* k  = (const float*)d_in[1];
  const float* v  = (const float*)d_in[2];
  const float* wq = (const float*)d_in[3];
  const float* wk = (const float*)d_in[4];
  const float* wv = (const float*)d_in[5];
  const float* wd = (const float*)d_in[6];
  const float* bd = (const float*)d_in[7];

  // ws layout (u16 elements): only weights + Qh/Kh + rsum + ctx now live in ws
  // (q/k/v are read as f32 directly by gemm_qkv — r12).
  // Vt lives in the OUTPUT buffer's aout region (dead until tail_fused) — r8 fix.
  u16* ws  = (u16*)d_ws;
  u16* ctx = ws + (size_t)BSD;         // bf16 attention context (kb region, kept for layout stability)
  u16* wqb = ws + 3L*BSD;              // wq, wk, wv contiguous bf16
  u16* wdb = wqb + 3L*WSZ;
  u16* Qh  = ws + 3L*BSD + 4L*WSZ;     // Qh, Kh contiguous (fused QK C-matrix)
  u16* Kh  = Qh + (size_t)BSD;
  float* rsum = (float*)(Kh + (size_t)BSD);
  float* out  = (float*)d_out;
  float* aout = out + (size_t)BSD;
  u16* Vt  = (u16*)aout;               // 12.6 MB scratch inside the 64 MB aout region

  // weights only (2.36M elems, ~3us); q/k/v cast happens inside gemm_qkv staging
  convert_w<<<dim3(1152), 256, 0, stream>>>(wq, wk, wv, wd, wqb);
  // fused Q+K+V projection, f32 A reg-staged (Q pre-scaled by log2e/8)
  gemm_qkv<<<dim3(192, 6), 256, 0, stream>>>(q, k, v, wqb, Qh, Vt, 768, 768, QSCALE);
  attn_fused<<<dim3(768), 256, 0, stream>>>(Qh, Kh, Vt, ctx, rsum);
  // attn_h0 + out-projection co-scheduled (r10): 1408 blocks, roles by bid%11
  tail_fused<<<dim3(1408), 256, 0, stream>>>(Qh, Kh, rsum, aout, ctx, wdb, out, bd);
}

// Round 13
// 291.685 us; speedup vs baseline: 1.0252x; 1.0252x over previous
//
#include <hip/hip_runtime.h>
#include <stdint.h>

typedef unsigned short u16;
typedef __attribute__((ext_vector_type(8))) __bf16 bf16x8;
typedef __attribute__((ext_vector_type(4))) float f32x4;

#define BSD 6291456   // 4*2048*768
#define WSZ 589824    // 768*768
#define QSCALE 0.18033688011112042f   // log2(e)/8, folded into Q projection

#if __has_builtin(__builtin_amdgcn_exp2f)
#define EXP2(x) __builtin_amdgcn_exp2f(x)
#else
#define EXP2(x) __builtin_exp2f(x)
#endif

__device__ __forceinline__ uint32_t fbits(float f) {
  union { float f; uint32_t u; } v; v.f = f; return v.u;
}
__device__ __forceinline__ u16 f2bf(float f) {           // RNE (epilogue scalar use only)
  uint32_t u = fbits(f);
  return (u16)((u + 0x7fff + ((u >> 16) & 1)) >> 16);
}
// round-to-nearest (half-up) bf16 pack of two floats via v_perm_b32: 3 insts / 2 values
__device__ __forceinline__ uint32_t pack_bf16rn(float lo, float hi) {
  return __builtin_amdgcn_perm(fbits(hi) + 0x8000u, fbits(lo) + 0x8000u, 0x07060302u);
}

__device__ __forceinline__ void load_lds16(const u16* g, u16* l) {
  __builtin_amdgcn_global_load_lds((__attribute__((address_space(1))) void*)(void*)g,
                                   (__attribute__((address_space(3))) void*)l, 16, 0, 0);
}

__device__ __forceinline__ f32x4 mfma16(bf16x8 a, bf16x8 b, f32x4 c) {
  return __builtin_amdgcn_mfma_f32_16x16x32_bf16(a, b, c, 0, 0, 0);
}

// ---------------- fp32 -> bf16 conversion of q,k,v + 4 weights ----------------
// r12 lesson (DO NOT REDO): folding this cast into the projection's staging
// (f32 reg-stage + pack + ds_write) made gemm_qkv 103us (MfmaUtil 10%) — the
// async global_load_lds DMA is what keeps the small-K gemm latency-tolerant.
__global__ void convert_all(const float* __restrict__ q, const float* __restrict__ k,
                            const float* __restrict__ v, const float* __restrict__ wq,
                            const float* __restrict__ wk, const float* __restrict__ wv,
                            const float* __restrict__ wd, u16* __restrict__ ws) {
  long e = ((long)blockIdx.x * blockDim.x + threadIdx.x) * 8;
  const float* src;
  if (e < (long)BSD) src = q + e;
  else if (e < 2L*BSD) src = k + (e - (long)BSD);
  else if (e < 3L*BSD) src = v + (e - 2L*BSD);
  else {
    long r = e - 3L*BSD;
    if (r < (long)WSZ) src = wq + r;
    else if (r < 2L*WSZ) src = wk + (r - (long)WSZ);
    else if (r < 3L*WSZ) src = wv + (r - 2L*WSZ);
    else src = wd + (r - 3L*WSZ);
  }
  float4 f0 = ((const float4*)src)[0];
  float4 f1 = ((const float4*)src)[1];
  uint4 o;
  o.x = pack_bf16rn(f0.x, f0.y);
  o.y = pack_bf16rn(f0.z, f0.w);
  o.z = pack_bf16rn(f1.x, f1.y);
  o.w = pack_bf16rn(f1.z, f1.w);
  *(uint4*)(ws + e) = o;
}

// ---------------- fused Q+K+V projection, dbuf single-barrier K-loop, BM=128 ----
// A rows (contiguous in ws): [0,8192)=q, [8192,16384)=k, [16384,24576)=v.
// Weights contiguous: wq | wk | wv.  Per-block role from m0:
//   q-rows: C = bf16(val*QSCALE) -> Qh   (row-major)
//   k-rows: C = bf16(val)        -> Kh   (= Qh + BSD, same row-major array)
//   v-rows: C = bf16(val) TRANSPOSED -> Vt [B=4,H=12,64,2048] (packed 8B stores)
// r8 lesson RESOLVED (r11): Vt lives in the OUTPUT buffer's aout region (dead
// until tail_fused) — no alias with any A row, so the fusion is race-free.
// r7 lesson: BM=128 (BM=64 halves per-wave A-reuse, ~3us loss).
__global__ __launch_bounds__(256) void gemm_qkv(const u16* __restrict__ A, const u16* __restrict__ Bw,
                                                u16* __restrict__ Cb, u16* __restrict__ Vt,
                                                int M, int N, int K, float oscale) {
  __shared__ u16 ldsA[2][128*32];
  __shared__ u16 ldsB[2][128*32];
  const int t = threadIdx.x, w = t >> 6, lane = t & 63, quad = lane >> 4, n16 = lane & 15;
  const int gx = gridDim.x, gy = gridDim.y;
  const int nb = gx * gy;
  int bx, by;
  if ((nb & 7) == 0) {
    int bid = (int)blockIdx.y * gx + (int)blockIdx.x;   // hw linear dispatch id
    int lid = (bid & 7) * (nb >> 3) + (bid >> 3);       // XCD-contiguous logical id
    bx = lid / gy; by = lid % gy;                       // same-bx blocks adjacent
  } else {
    bx = blockIdx.x; by = blockIdx.y;
  }
  const int m0 = bx * 128, n0 = by * 128;
  const int wr = (w >> 1) * 64, wc = (w & 1) * 64;
  const u16* Bm = Bw;
  float sc = oscale;
  int vsel = 0;
  if (m0 >= 16384)     { Bm = Bw + 2*WSZ; sc = 1.0f; vsel = 1; }
  else if (m0 >= 8192) { Bm = Bw + WSZ;   sc = 1.0f; }
  auto stage = [&](int k0, int bs) {
#pragma unroll
    for (int j = 0; j < 2; ++j) {
      int slot = j*256 + t;                 // lane-linear LDS dst
      int row = slot >> 2, ch = slot & 3;
      load_lds16(A  + (size_t)(m0 + row)*K + k0 + ch*8, &ldsA[bs][0] + slot*8);
      load_lds16(Bm + (size_t)(n0 + row)*K + k0 + ch*8, &ldsB[bs][0] + slot*8);
    }
  };
  f32x4 acc[4][4] = {};
  const int NK = K >> 5;
  stage(0, 0);
#pragma unroll 1
  for (int ks = 0; ks < NK; ++ks) {
    __syncthreads();                        // tile ks staged; prior reads of buf[(ks+1)&1] done
    if (ks + 1 < NK) stage((ks + 1) << 5, (ks + 1) & 1);   // prefetch overlaps compute
    const u16* As = &ldsA[ks & 1][0];
    const u16* Bs = &ldsB[ks & 1][0];
    bf16x8 af[4], bf[4];
#pragma unroll
    for (int i = 0; i < 4; ++i) {
      af[i] = *(const bf16x8*)(As + (wr + i*16 + n16)*32 + quad*8);
      bf[i] = *(const bf16x8*)(Bs + (wc + i*16 + n16)*32 + quad*8);
    }
#pragma unroll
    for (int mi = 0; mi < 4; ++mi)
#pragma unroll
      for (int ni = 0; ni < 4; ++ni)
        acc[mi][ni] = mfma16(af[mi], bf[ni], acc[mi][ni]);
  }
#pragma unroll
  for (int mi = 0; mi < 4; ++mi)
#pragma unroll
    for (int ni = 0; ni < 4; ++ni) {
      if (vsel) {
        int c = n0 + wc + ni*16 + n16;                 // feature 0..767
        int hh = c >> 6, d = c & 63;
        int m = m0 + wr + mi*16 + quad*4 - 16384;      // v tokens 0..8191
        int bI = m >> 11, s = m & 2047;
        uint2 pk;
        pk.x = pack_bf16rn(acc[mi][ni][0], acc[mi][ni][1]);
        pk.y = pack_bf16rn(acc[mi][ni][2], acc[mi][ni][3]);
        *(uint2*)(Vt + ((size_t)(bI*12 + hh)*64 + d)*2048 + s) = pk;
      } else {
#pragma unroll
        for (int i = 0; i < 4; ++i) {
          size_t r = (size_t)m0 + wr + mi*16 + quad*4 + i;   // C/D: row=(lane>>4)*4+i
          size_t c = (size_t)n0 + wc + ni*16 + n16;          //      col=lane&15
          Cb[r*(size_t)N + c] = f2bf(acc[mi][ni][i] * sc);
        }
      }
    }
}

// ---------------- fused attention (r5-r11 structure, measured 67-70 us) ----------
__global__ __launch_bounds__(256, 3) void attn_fused(const u16* __restrict__ Qh, const u16* __restrict__ Kh,
                                                     const u16* __restrict__ Vt, u16* __restrict__ ctx,
                                                     float* __restrict__ rowsum) {
  __shared__ u16 ldsK[2*64*64];    // [buf][n][8 chunks of 8 u16], chunk XOR-swizzled by n&7
  __shared__ u16 ldsV[2*64*64];    // [buf][d][8 chunks],          swizzled by d&7
  __shared__ u16 ldsP[128*64];     // [m][8 b128-chunks],          swizzled by m&7; wave-private rows
  const int bid = blockIdx.x;
  const int lid = (bid & 7) * 96 + (bid >> 3);   // XCD-contiguous logical id (bijective, 768%8==0)
  const int pair = lid >> 4;            // 0..47 = (b,h)
  const int qt = lid & 15;              // q-tile
  const int h = pair % 12, b = pair / 12;
  const int q0 = qt * 128;
  const int t = threadIdx.x, w = t >> 6, lane = t & 63, quad = lane >> 4, n16 = lane & 15;
  const int sw = n16 & 7;
  const u16* Kbh = Kh + (size_t)b*2048*768 + h*64;
  const u16* Vbh = Vt + (size_t)(b*12 + h)*64*2048;
  auto stage = [&](int c, int bsel) {
#pragma unroll
    for (int jj = 0; jj < 2; ++jj) {
      int slot = jj*256 + t;                // lane-linear LDS dst
      int n = slot >> 3, cg = (slot & 7) ^ (n & 7);
      load_lds16(Kbh + (size_t)(c*64 + n)*768 + cg*8, ldsK + bsel*4096 + slot*8);
      load_lds16(Vbh + (size_t)n*2048 + c*64 + cg*8, ldsV + bsel*4096 + slot*8);
    }
  };
  // loop-invariant LDS element offsets (u16 units)
  int koff[4][2], voff[2][4], prd[2][2], pwr[2], pwc[4];
#pragma unroll
  for (int ni = 0; ni < 4; ++ni) {
    koff[ni][0] = (ni*16 + n16)*64 + ((quad ^ sw) * 8);
    koff[ni][1] = (ni*16 + n16)*64 + (((4 + quad) ^ sw) * 8);
    pwc[ni] = ((ni*2 + (quad >> 1)) ^ sw) * 8;
  }
#pragma unroll
  for (int kt = 0; kt < 2; ++kt)
#pragma unroll
    for (int di = 0; di < 4; ++di)
      voff[kt][di] = (di*16 + n16)*64 + (((kt*4 + quad) ^ sw) * 8);
#pragma unroll
  for (int mi = 0; mi < 2; ++mi) {
    pwr[mi] = (w*32 + mi*16 + n16)*64 + (quad & 1)*4;
    prd[mi][0] = (w*32 + mi*16 + n16)*64 + ((quad ^ sw) * 8);
    prd[mi][1] = (w*32 + mi*16 + n16)*64 + (((4 + quad) ^ sw) * 8);
  }
  bf16x8 qf[2][2];                 // Q frags (pre-scaled by log2e/8) in regs all kernel
#pragma unroll
  for (int mi = 0; mi < 2; ++mi)
#pragma unroll
    for (int ks = 0; ks < 2; ++ks)
      qf[mi][ks] = *(const bf16x8*)(Qh + (size_t)(b*2048 + q0 + w*32 + mi*16 + n16)*768
                                       + h*64 + ks*32 + quad*8);
  // all-ones B fragment: racc += P @ ones gives rowsums on the MFMA pipe,
  // replicated across n16 and already in C-layout rows (quad*4+i).
  union { uint32_t u[4]; bf16x8 v; } onesu = {{0x3F803F80u, 0x3F803F80u, 0x3F803F80u, 0x3F803F80u}};
  const bf16x8 ones = onesu.v;
  f32x4 oacc[2][4] = {};
  f32x4 racc[2] = {};
  stage(0, 0);
#pragma unroll 1
  for (int c = 0; c < 32; ++c) {
    __syncthreads();                        // chunk c staged (vmcnt drain); prior reads of buf[(c+1)&1] done
    if (c < 31) stage(c + 1, (c + 1) & 1);  // prefetch overlaps this chunk's compute
    const int bs = (c & 1) * 4096;
    const u16* K0 = ldsK + bs;
    const u16* V0 = ldsV + bs;
    f32x4 sacc[4][2] = {};
    __builtin_amdgcn_s_setprio(1);
#pragma unroll
    for (int ni = 0; ni < 4; ++ni) {
      bf16x8 kf0 = *(const bf16x8*)(K0 + koff[ni][0]);
      bf16x8 kf1 = *(const bf16x8*)(K0 + koff[ni][1]);
#pragma unroll
      for (int mi = 0; mi < 2; ++mi) {
        sacc[ni][mi] = mfma16(kf0, qf[mi][0], sacc[ni][mi]);   // S^T = K.Q^T
        sacc[ni][mi] = mfma16(kf1, qf[mi][1], sacc[ni][mi]);
      }
    }
    __builtin_amdgcn_s_setprio(0);
    // exp2 (Q pre-scaled -> 1 v_exp each) + native-cast bf16 pack (no VALU rowsum)
#pragma unroll
    for (int mi = 0; mi < 2; ++mi) {
#pragma unroll
      for (int ni = 0; ni < 4; ++ni) {
        float p0 = EXP2(sacc[ni][mi][0]);
        float p1 = EXP2(sacc[ni][mi][1]);
        float p2 = EXP2(sacc[ni][mi][2]);
        float p3 = EXP2(sacc[ni][mi][3]);
        union { __bf16 bx[4]; uint2 v; } pk;
        pk.bx[0] = (__bf16)p0;
        pk.bx[1] = (__bf16)p1;
        pk.bx[2] = (__bf16)p2;
        pk.bx[3] = (__bf16)p3;
        *(uint2*)(ldsP + pwr[mi] + pwc[ni]) = pk.v;
      }
    }
    // PV: A = P (wave-private rows, no barrier), B = V^T chunk; rowsum rides along.
#pragma unroll
    for (int kt = 0; kt < 2; ++kt) {
      bf16x8 vf[4], pf[2];
#pragma unroll
      for (int di = 0; di < 4; ++di)
        vf[di] = *(const bf16x8*)(V0 + voff[kt][di]);
#pragma unroll
      for (int mi = 0; mi < 2; ++mi)
        pf[mi] = *(const bf16x8*)(ldsP + prd[mi][kt]);
      __builtin_amdgcn_s_setprio(1);
#pragma unroll
      for (int mi = 0; mi < 2; ++mi) {
        racc[mi] = mfma16(pf[mi], ones, racc[mi]);
#pragma unroll
        for (int di = 0; di < 4; ++di)
          oacc[mi][di] = mfma16(pf[mi], vf[di], oacc[mi][di]);
      }
      __builtin_amdgcn_s_setprio(0);
    }
  }
  // racc[mi][i] = full rowsum for row quad*4+i (replicated over n16) — matches oacc layout
  float invr[2][4];
#pragma unroll
  for (int mi = 0; mi < 2; ++mi)
#pragma unroll
    for (int i = 0; i < 4; ++i)
      invr[mi][i] = 1.0f / racc[mi][i];
#pragma unroll
  for (int mi = 0; mi < 2; ++mi)
#pragma unroll
    for (int di = 0; di < 4; ++di)
#pragma unroll
      for (int i = 0; i < 4; ++i) {
        size_t r = (size_t)b*2048 + q0 + w*32 + mi*16 + quad*4 + i;
        int cc = h*64 + di*16 + n16;
        ctx[r*768 + cc] = f2bf(oacc[mi][di][i] * invr[mi][i]);
      }
  if (h == 0 && n16 == 0) {
#pragma unroll
    for (int mi = 0; mi < 2; ++mi)
#pragma unroll
      for (int i = 0; i < 4; ++i)
        rowsum[b*2048 + q0 + w*32 + mi*16 + quad*4 + i] = racc[mi][i];
  }
}

// ---------------- tail_fused: attn_h0 + out-projection in ONE launch (r10 win) ----
__global__ __launch_bounds__(256) void tail_fused(const u16* __restrict__ Qh, const u16* __restrict__ Kh,
                                                  const float* __restrict__ rowsum, float* __restrict__ aout,
                                                  const u16* __restrict__ ctx, const u16* __restrict__ wdb,
                                                  float* __restrict__ out, const float* __restrict__ bias) {
  __shared__ __align__(16) u16 shmem[16384];   // 32 KB; h0 uses 16 KB, gemm all 32 KB
  const int bid = blockIdx.x;
  const int grp = bid / 11, off = bid % 11;
  const int t = threadIdx.x, w = t >> 6, lane = t & 63, quad = lane >> 4, n16 = lane & 15;
  if (off < 8) {
    // ---- h0 role: recompute QK^T for h=0, scale by 1/rowsum ----
    const int idx = grp * 8 + off;            // 0..1023
    const int qt = idx & 15, kt = (idx >> 4) & 15, b = idx >> 8;
    const int q0 = qt * 128;
    u16* ldsK = shmem;                        // [128][64]
    const u16* Kbh = Kh + (size_t)b*2048*768; // h = 0
    bf16x8 qf[2][2];
#pragma unroll
    for (int mi = 0; mi < 2; ++mi)
#pragma unroll
      for (int ks = 0; ks < 2; ++ks)
        qf[mi][ks] = *(const bf16x8*)(Qh + (size_t)(b*2048 + q0 + w*32 + mi*16 + n16)*768
                                         + ks*32 + quad*8);
#pragma unroll
    for (int j = 0; j < 4; ++j) {
      int slot = j*256 + w*64 + lane;
      int n = slot >> 3, cs = slot & 7, cg = cs ^ (n & 7);
      load_lds16(Kbh + (size_t)(kt*128 + n)*768 + cg*8, ldsK + slot*8);
    }
    __syncthreads();
    f32x4 sacc[2][8] = {};
#pragma unroll
    for (int ni = 0; ni < 8; ++ni) {
      int n = ni*16 + n16;
      bf16x8 kf0 = *(const bf16x8*)(ldsK + n*64 + ((quad)     ^ (n & 7))*8);
      bf16x8 kf1 = *(const bf16x8*)(ldsK + n*64 + ((4 + quad) ^ (n & 7))*8);
#pragma unroll
      for (int mi = 0; mi < 2; ++mi) {
        sacc[mi][ni] = mfma16(qf[mi][0], kf0, sacc[mi][ni]);
        sacc[mi][ni] = mfma16(qf[mi][1], kf1, sacc[mi][ni]);
      }
    }
    float inv[2][4];
#pragma unroll
    for (int mi = 0; mi < 2; ++mi)
#pragma unroll
      for (int i = 0; i < 4; ++i)
        inv[mi][i] = 1.0f / rowsum[b*2048 + q0 + w*32 + mi*16 + quad*4 + i];
#pragma unroll
    for (int mi = 0; mi < 2; ++mi)
#pragma unroll
      for (int ni = 0; ni < 8; ++ni)
#pragma unroll
        for (int i = 0; i < 4; ++i) {
          size_t r = (size_t)b*2048 + q0 + w*32 + mi*16 + quad*4 + i;
          size_t cc = (size_t)kt*128 + ni*16 + n16;
          aout[r*2048 + cc] = EXP2(sacc[mi][ni][i]) * inv[mi][i];   // Qh pre-scaled
        }
  } else {
    // ---- out-projection role: out = ctx @ wd^T + bias (BM=128, dbuf K-loop) ----
    const int idx = grp * 3 + (off - 8);      // 0..383
    const int bx = idx & 63, by = idx >> 6;   // (64,6)
    const int m0 = bx * 128, n0 = by * 128;
    const int wr = (w >> 1) * 64, wc = (w & 1) * 64;
    const int K = 768, N = 768;
    u16* ldsA = shmem;                        // [2][128*32] = 8192 u16
    u16* ldsB = shmem + 8192;                 // [2][128*32]
    auto stage = [&](int k0, int bs) {
#pragma unroll
      for (int j = 0; j < 2; ++j) {
        int slot = j*256 + t;
        int row = slot >> 2, ch = slot & 3;
        load_lds16(ctx + (size_t)(m0 + row)*K + k0 + ch*8, ldsA + bs*4096 + slot*8);
        load_lds16(wdb + (size_t)(n0 + row)*K + k0 + ch*8, ldsB + bs*4096 + slot*8);
      }
    };
    f32x4 acc[4][4] = {};
    stage(0, 0);
#pragma unroll 1
    for (int ks = 0; ks < 24; ++ks) {
      __syncthreads();
      if (ks + 1 < 24) stage((ks + 1) << 5, (ks + 1) & 1);
      const u16* As = ldsA + (ks & 1)*4096;
      const u16* Bs = ldsB + (ks & 1)*4096;
      bf16x8 af[4], bf[4];
#pragma unroll
      for (int i = 0; i < 4; ++i) {
        af[i] = *(const bf16x8*)(As + (wr + i*16 + n16)*32 + quad*8);
        bf[i] = *(const bf16x8*)(Bs + (wc + i*16 + n16)*32 + quad*8);
      }
#pragma unroll
      for (int mi = 0; mi < 4; ++mi)
#pragma unroll
        for (int ni = 0; ni < 4; ++ni)
          acc[mi][ni] = mfma16(af[mi], bf[ni], acc[mi][ni]);
    }
#pragma unroll
    for (int mi = 0; mi < 4; ++mi)
#pragma unroll
      for (int ni = 0; ni < 4; ++ni)
#pragma unroll
        for (int i = 0; i < 4; ++i) {
          size_t r = (size_t)m0 + wr + mi*16 + quad*4 + i;
          size_t c = (size_t)n0 + wc + ni*16 + n16;
          out[r*(size_t)N + c] = acc[mi][ni][i] + bias[c];
        }
  }
}

extern "C" void kernel_launch(void* const* d_in, const int* in_sizes, int n_in,
                              void* d_out, int out_size, void* d_ws, size_t ws_size,
                              hipStream_t stream) {
  (void)in_sizes; (void)n_in; (void)out_size; (void)ws_size;
  const float* q  = (const float*)d_in[0];
  const float* k  = (const float*)d_in[1];
  const float* v  = (const float*)d_in[2];
  const float* wq = (const float*)d_in[3];
  const float* wk = (const float*)d_in[4];
  const float* wv = (const float*)d_in[5];
  const float* wd = (const float*)d_in[6];
  const float* bd = (const float*)d_in[7];

  // ws layout (u16 elements), high-water ~67.7 MB:
  //   kb -> ctx  (kb dead after fused QKV projection)
  // Vt lives in the OUTPUT buffer's aout region (dead until tail_fused writes it)
  // — this is what makes the single-launch QKV projection race-free (r8 fix).
  u16* ws  = (u16*)d_ws;
  u16* kb  = ws + (size_t)BSD;         // rows 8192..16383 of fused QKV A-matrix
  u16* wqb = ws + 3L*BSD;              // wq, wk, wv contiguous
  u16* wdb = wqb + 3L*WSZ;
  u16* Qh  = ws + 3L*BSD + 4L*WSZ;     // Qh, Kh contiguous (fused QK C-matrix)
  u16* Kh  = Qh + (size_t)BSD;
  float* rsum = (float*)(Kh + (size_t)BSD);
  u16* ctx = kb;
  float* out  = (float*)d_out;
  float* aout = out + (size_t)BSD;
  u16* Vt  = (u16*)aout;               // 12.6 MB scratch inside the 64 MB aout region

  convert_all<<<dim3(10368), 256, 0, stream>>>(q, k, v, wq, wk, wv, wd, ws);
  // fused Q+K+V projection in ONE launch (Q pre-scaled by log2e/8):
  // 1152 blocks ~ 4.5/CU; V-blocks backfill as QK-blocks drain (r10 mechanism).
  gemm_qkv<<<dim3(192, 6), 256, 0, stream>>>(ws, wqb, Qh, Vt, 24576, 768, 768, QSCALE);
  attn_fused<<<dim3(768), 256, 0, stream>>>(Qh, Kh, Vt, ctx, rsum);
  // attn_h0 + out-projection co-scheduled (r10): 1408 blocks, roles by bid%11
  tail_fused<<<dim3(1408), 256, 0, stream>>>(Qh, Kh, rsum, aout, ctx, wdb, out, bd);
}